// Round 10
// baseline (386.460 us; speedup 1.0000x reference)
//
#include <hip/hip_runtime.h>

#define NB 64
#define NS 2048
#define ND 64
#define KSTEP 64
#define NIT (NS / KSTEP)  // 32

typedef __bf16 bf16x8 __attribute__((ext_vector_type(8)));
typedef float f32x4 __attribute__((ext_vector_type(4)));
typedef unsigned int u32;
typedef u32 u32x2 __attribute__((ext_vector_type(2)));
typedef u32 u32x4 __attribute__((ext_vector_type(4)));
typedef unsigned short u16;
typedef u16 u16x8 __attribute__((ext_vector_type(8)));

#define C2F 0.18033688011112042f  // log2(e)/8

__device__ __forceinline__ float fexp2(float x) { return exp2f(x); }
__device__ __forceinline__ float flog2(float x) { return log2f(x); }

// Barrier without the vmcnt(0) drain __syncthreads imposes (r8: -55us).
#define TILE_BARRIER()                                   \
  do {                                                   \
    asm volatile("s_waitcnt lgkmcnt(0)" ::: "memory");   \
    __builtin_amdgcn_s_barrier();                        \
    asm volatile("" ::: "memory");                       \
  } while (0)

__device__ __forceinline__ u16 f2bs(float x) {
  __bf16 h = (__bf16)x;
  return __builtin_bit_cast(u16, h);
}

// packed f32x2 -> bf16x2 (RNE), single instruction
__device__ __forceinline__ u32 cvt_pk_bf16(float lo, float hi) {
  u32 r;
  asm("v_cvt_pk_bf16_f32 %0, %1, %2" : "=v"(r) : "v"(lo), "v"(hi));
  return r;
}

__device__ __forceinline__ bf16x8 cvt8(f32x4 a, f32x4 b) {
  bf16x8 r;
  r[0] = (__bf16)a[0]; r[1] = (__bf16)a[1]; r[2] = (__bf16)a[2]; r[3] = (__bf16)a[3];
  r[4] = (__bf16)b[0]; r[5] = (__bf16)b[1]; r[6] = (__bf16)b[2]; r[7] = (__bf16)b[3];
  return r;
}

// ---------- fused prep: [0,4096) K-cast | [4096,6144) V-transpose | [6144,6656) mask-pack ----------
// V^T column permutation within each 32-k window: position p holds
// k_local = 16*((p>>2)&1) + 4*((p>>3)&3) + (p&3), so the kernel's PV
// A-operand is ONE ds_read_b128 at col 8g..8g+7 per 32-window.
__global__ __launch_bounds__(256) void prep_fused(const float* __restrict__ K,
                                                  const float* __restrict__ V,
                                                  const int* __restrict__ M,
                                                  u16* __restrict__ Kbf,
                                                  u16* __restrict__ VT,
                                                  u32* __restrict__ Mb) {
  __shared__ __attribute__((aligned(16))) u16 T[64][72];
  const int bid = blockIdx.x;
  if (bid < 4096) {
    const size_t i = ((size_t)bid * 256 + threadIdx.x) * 8;
    f32x4 a = __builtin_nontemporal_load((const f32x4*)(K + i));
    f32x4 b = __builtin_nontemporal_load((const f32x4*)(K + i + 4));
    *(bf16x8*)(Kbf + i) = cvt8(a, b);
  } else if (bid < 6144) {
    const int vbid = bid - 4096;
    const int b = vbid >> 5, kt = vbid & 31;
    const float* src = V + ((size_t)b * NS + kt * 64) * ND;
    {
      const int k = threadIdx.x >> 2, d0 = (threadIdx.x & 3) * 16;
      const float* p = src + (size_t)k * ND + d0;
      f32x4 a0 = __builtin_nontemporal_load((const f32x4*)p);
      f32x4 a1 = __builtin_nontemporal_load((const f32x4*)(p + 4));
      f32x4 a2 = __builtin_nontemporal_load((const f32x4*)(p + 8));
      f32x4 a3 = __builtin_nontemporal_load((const f32x4*)(p + 12));
      *(bf16x8*)&T[k][d0]     = cvt8(a0, a1);
      *(bf16x8*)&T[k][d0 + 8] = cvt8(a2, a3);
    }
    __syncthreads();
    const int d = threadIdx.x >> 2, k0 = (threadIdx.x & 3) * 16;
    u16x8 r0, r1;
#pragma unroll
    for (int j = 0; j < 8; ++j) {
      const int P0 = k0 + j, P1 = k0 + 8 + j;
      const int s0 = 32 * (P0 >> 5) + 16 * ((P0 >> 2) & 1) + 4 * ((P0 >> 3) & 3) + (P0 & 3);
      const int s1 = 32 * (P1 >> 5) + 16 * ((P1 >> 2) & 1) + 4 * ((P1 >> 3) & 3) + (P1 & 3);
      r0[j] = T[s0][d];
      r1[j] = T[s1][d];
    }
    u16* dst = VT + ((size_t)b * ND + d) * NS + kt * 64 + k0;
    *(u16x8*)dst = r0;
    *(u16x8*)(dst + 8) = r1;
  } else {
    // mask-pack: each thread packs 32 ints -> one u32 (bit i = element i)
    const int tg = (bid - 6144) * 256 + threadIdx.x;
    const int4* p = (const int4*)(M + (size_t)tg * 32);
    u32 bits = 0;
#pragma unroll
    for (int j = 0; j < 8; ++j) {
      int4 m = p[j];
      bits |= (u32)(m.x != 0) << (4 * j);
      bits |= (u32)(m.y != 0) << (4 * j + 1);
      bits |= (u32)(m.z != 0) << (4 * j + 2);
      bits |= (u32)(m.w != 0) << (4 * j + 3);
    }
    Mb[tg] = bits;
  }
}

// K-SPLIT structure (r9, 346us): 512 thr / 8 waves / 64 q-rows, 2048 blocks.
// Waves (wq, kt): wq = w&3 -> 16-q-row subtile; kt = w>>2 -> k-half of each
// 64-k tile. 3 blk/CU -> 3 batches resident/XCD -> bf16 K/V L2-resident.
// mfma_f32_16x16x32_bf16 facts (HW-verified r1-2): A[row=l&15][k=8g+s],
// B[k=8g+s][col=l&15], D[m=4g+reg][n=l&15]. QK^T role-swapped (A=K,B=Q):
// lane owns W[q=c][k=kt*32+16j+4g+r]; W feeds PV's B-operand from registers.
template <bool PRE>
__global__ __launch_bounds__(512, 3) void DotProductAttention_22436909154804_kernel(
    const float* __restrict__ Q, const float* __restrict__ K,
    const float* __restrict__ V, const int* __restrict__ M,
    const u16* __restrict__ Kbf, const u16* __restrict__ VTbf,
    const u32* __restrict__ Mb, float* __restrict__ ctx, float* __restrict__ wts) {
  __shared__ __attribute__((aligned(16))) u16 Kt[2][64][72];  // [k][d]
  __shared__ __attribute__((aligned(16))) u16 Vt[2][64][72];  // [d][perm k]
  __shared__ float Rs[2][64];

  const int tid  = threadIdx.x;
  const int lane = tid & 63;
  const int w    = tid >> 6;   // 0..7
  const int wq   = w & 3;      // q-subtile
  const int kt   = w >> 2;     // k-half
  const int g    = lane >> 4;  // 0..3
  const int c    = lane & 15;  // 0..15

  // XCD swizzle: 2048 blocks = 8 XCDs x 256; consecutive vb share a batch.
  const int bid = blockIdx.x;
  const int vb  = (bid & 7) * 256 + (bid >> 3);
  const int b   = vb >> 5;
  const int qt  = vb & 31;
  const int q0w = qt * 64 + wq * 16;
  const size_t bq = (size_t)b * NS;

  // Q B-frags
  const float* qp = Q + (bq + q0w + c) * ND + 8 * g;
  f32x4 qa = __builtin_nontemporal_load((const f32x4*)qp);
  f32x4 qb = __builtin_nontemporal_load((const f32x4*)(qp + 4));
  const bf16x8 qf0 = cvt8(qa, qb);
  qa = __builtin_nontemporal_load((const f32x4*)(qp + 32));
  qb = __builtin_nontemporal_load((const f32x4*)(qp + 36));
  const bf16x8 qf1 = cvt8(qa, qb);

  const u16* Kbb = PRE ? (Kbf + bq * ND) : (const u16*)nullptr;
  const u16* VTb = PRE ? (VTbf + bq * ND) : (const u16*)nullptr;
  const float* Kb32 = K + bq * ND;
  const float* Vb32 = V + bq * ND;
  const int* Mr  = M + (size_t)(q0w + c) * NS + kt * 32;
  const u32* Mbr = Mb + (size_t)(q0w + c) * (NS / 32) + kt;

  const bool isK = tid < 256;
  const int st   = tid & 255;

  auto msel = [](float e, u32 mm, int idx) -> float {
    u32 keep = (u32)(((int)(mm << (31 - idx))) >> 31);
    return __uint_as_float(__float_as_uint(e) & keep);
  };

  // ---- staging ----
  u16x8 sp0, sp1;            // PRE payloads
  f32x4 kf0, kf1, kf2, kf3;  // !PRE payloads
  auto issueK1 = [&](int kb) {  // phase 1: K tile only
    if (PRE) {
      const int r = tid >> 3, cc = (tid & 7) * 8;
      sp0 = *(const u16x8*)(Kbb + (size_t)(kb + r) * ND + cc);
    } else if (isK) {
      const int r = st >> 2, cc = (st & 3) * 16;
      const float* p = Kb32 + (size_t)(kb + r) * ND + cc;
      kf0 = *(const f32x4*)p;       kf1 = *(const f32x4*)(p + 4);
      kf2 = *(const f32x4*)(p + 8); kf3 = *(const f32x4*)(p + 12);
    }
  };
  auto writeK1 = [&](int buf) {
    if (PRE) {
      const int r = tid >> 3, cc = (tid & 7) * 8;
      *(u16x8*)&Kt[buf][r][cc] = sp0;
    } else if (isK) {
      const int r = st >> 2, cc = (st & 3) * 16;
      *(bf16x8*)&Kt[buf][r][cc]     = cvt8(kf0, kf1);
      *(bf16x8*)&Kt[buf][r][cc + 8] = cvt8(kf2, kf3);
    }
  };
  auto issueKV = [&](int kb) {  // phase 2: K by waves 0-3, V by waves 4-7
    if (PRE) {
      if (isK) {
        const int r = st >> 2, cc = (st & 3) * 16;
        const u16* p = Kbb + (size_t)(kb + r) * ND + cc;
        sp0 = *(const u16x8*)p; sp1 = *(const u16x8*)(p + 8);
      } else {
        const int d = st >> 2, kc = (st & 3) * 16;
        const u16* p = VTb + (size_t)d * NS + kb + kc;
        sp0 = *(const u16x8*)p; sp1 = *(const u16x8*)(p + 8);
      }
    } else {
      if (isK) {
        const int r = st >> 2, cc = (st & 3) * 16;
        const float* p = Kb32 + (size_t)(kb + r) * ND + cc;
        kf0 = *(const f32x4*)p;       kf1 = *(const f32x4*)(p + 4);
        kf2 = *(const f32x4*)(p + 8); kf3 = *(const f32x4*)(p + 12);
      } else {
        const int k = st >> 2, d0 = (st & 3) * 16;
        const float* p = Vb32 + (size_t)(kb + k) * ND + d0;
        kf0 = *(const f32x4*)p;       kf1 = *(const f32x4*)(p + 4);
        kf2 = *(const f32x4*)(p + 8); kf3 = *(const f32x4*)(p + 12);
      }
    }
  };
  auto writeKV = [&](int buf) {
    if (PRE) {
      if (isK) {
        const int r = st >> 2, cc = (st & 3) * 16;
        *(u16x8*)&Kt[buf][r][cc] = sp0; *(u16x8*)&Kt[buf][r][cc + 8] = sp1;
      } else {
        const int d = st >> 2, kc = (st & 3) * 16;
        *(u16x8*)&Vt[buf][d][kc] = sp0; *(u16x8*)&Vt[buf][d][kc + 8] = sp1;
      }
    } else {
      if (isK) {
        const int r = st >> 2, cc = (st & 3) * 16;
        *(bf16x8*)&Kt[buf][r][cc]     = cvt8(kf0, kf1);
        *(bf16x8*)&Kt[buf][r][cc + 8] = cvt8(kf2, kf3);
      } else {
        const int k = st >> 2, d0 = (st & 3) * 16;
        bf16x8 v0 = cvt8(kf0, kf1), v1 = cvt8(kf2, kf3);
#pragma unroll
        for (int j = 0; j < 8; ++j) {
          Vt[buf][d0 + j][k]     = __builtin_bit_cast(u16, v0[j]);
          Vt[buf][d0 + 8 + j][k] = __builtin_bit_cast(u16, v1[j]);
        }
      }
    }
  };

  const f32x4 zz = {0.f, 0.f, 0.f, 0.f};

  // ---------------- Phase 1: row sums (per k-half) ----------------
  float rs = 0.f;
  issueK1(0);
  writeK1(0);
  __syncthreads();
  for (int it = 0; it < NIT; ++it) {
    const int cur = it & 1, kb = it * KSTEP;
    if (it + 1 < NIT) issueK1(kb + KSTEP);
    u32 mm = 0;
    if (PRE) mm = Mbr[kb >> 5];
#pragma unroll
    for (int j = 0; j < 2; ++j) {
      bf16x8 a0 = *(const bf16x8*)&Kt[cur][kt * 32 + 16 * j + c][8 * g];
      bf16x8 a1 = *(const bf16x8*)&Kt[cur][kt * 32 + 16 * j + c][32 + 8 * g];
      __builtin_amdgcn_s_setprio(1);
      f32x4 s = __builtin_amdgcn_mfma_f32_16x16x32_bf16(a0, qf0, zz, 0, 0, 0);
      s = __builtin_amdgcn_mfma_f32_16x16x32_bf16(a1, qf1, s, 0, 0, 0);
      __builtin_amdgcn_s_setprio(0);
      if (PRE) {
        rs += msel(fexp2(s[0] * C2F), mm, 16 * j + 4 * g + 0)
            + msel(fexp2(s[1] * C2F), mm, 16 * j + 4 * g + 1)
            + msel(fexp2(s[2] * C2F), mm, 16 * j + 4 * g + 2)
            + msel(fexp2(s[3] * C2F), mm, 16 * j + 4 * g + 3);
      } else {
        const int4 m4 = *(const int4*)(Mr + kb + 16 * j + 4 * g);
        rs += (m4.x ? fexp2(s[0] * C2F) : 0.f)
            + (m4.y ? fexp2(s[1] * C2F) : 0.f)
            + (m4.z ? fexp2(s[2] * C2F) : 0.f)
            + (m4.w ? fexp2(s[3] * C2F) : 0.f);
      }
    }
    if (it + 1 < NIT) writeK1((it + 1) & 1);
    TILE_BARRIER();
  }
  rs += __shfl_xor(rs, 16);
  rs += __shfl_xor(rs, 32);
  issueKV(0);
  if (lane < 16) Rs[kt][wq * 16 + c] = rs;
  __syncthreads();
  const float l2inv = -flog2(Rs[0][wq * 16 + c] + Rs[1][wq * 16 + c]);
  writeKV(0);
  __syncthreads();

  // ---------------- Phase 2: weights + PV (per k-half partials) ----------------
  f32x4 acc[4] = {zz, zz, zz, zz};
  float* wrow = wts + (bq + q0w + c) * NS + kt * 32;
  for (int it = 0; it < NIT; ++it) {
    const int cur = it & 1, kb = it * KSTEP;
    if (it + 1 < NIT) issueKV(kb + KSTEP);
    u32 mm = 0;
    if (PRE) mm = Mbr[kb >> 5];

    u32 wpk[4];
#pragma unroll
    for (int j = 0; j < 2; ++j) {
      bf16x8 a0 = *(const bf16x8*)&Kt[cur][kt * 32 + 16 * j + c][8 * g];
      bf16x8 a1 = *(const bf16x8*)&Kt[cur][kt * 32 + 16 * j + c][32 + 8 * g];
      __builtin_amdgcn_s_setprio(1);
      f32x4 s = __builtin_amdgcn_mfma_f32_16x16x32_bf16(a0, qf0, zz, 0, 0, 0);
      s = __builtin_amdgcn_mfma_f32_16x16x32_bf16(a1, qf1, s, 0, 0, 0);
      __builtin_amdgcn_s_setprio(0);
      float w0, w1, w2, w3;
      if (PRE) {
        w0 = msel(fexp2(fmaf(s[0], C2F, l2inv)), mm, 16 * j + 4 * g + 0);
        w1 = msel(fexp2(fmaf(s[1], C2F, l2inv)), mm, 16 * j + 4 * g + 1);
        w2 = msel(fexp2(fmaf(s[2], C2F, l2inv)), mm, 16 * j + 4 * g + 2);
        w3 = msel(fexp2(fmaf(s[3], C2F, l2inv)), mm, 16 * j + 4 * g + 3);
      } else {
        const int4 m4 = *(const int4*)(Mr + kb + 16 * j + 4 * g);
        w0 = m4.x ? fexp2(fmaf(s[0], C2F, l2inv)) : 0.f;
        w1 = m4.y ? fexp2(fmaf(s[1], C2F, l2inv)) : 0.f;
        w2 = m4.z ? fexp2(fmaf(s[2], C2F, l2inv)) : 0.f;
        w3 = m4.w ? fexp2(fmaf(s[3], C2F, l2inv)) : 0.f;
      }
      f32x4 wv = {w0, w1, w2, w3};
      __builtin_nontemporal_store(wv, (f32x4*)(wrow + kb + 16 * j + 4 * g));
      wpk[2 * j]     = cvt_pk_bf16(w0, w1);
      wpk[2 * j + 1] = cvt_pk_bf16(w2, w3);
    }

    // PV partial for this wave's k-half; B = W from registers
    u32x4 wu = {wpk[0], wpk[1], wpk[2], wpk[3]};
    bf16x8 wb = __builtin_bit_cast(bf16x8, wu);
    __builtin_amdgcn_s_setprio(1);
#pragma unroll
    for (int dt = 0; dt < 4; ++dt) {
      bf16x8 va;
      if (PRE) {
        va = *(const bf16x8*)&Vt[cur][dt * 16 + c][kt * 32 + 8 * g];
      } else {
        u32x2 vlo = *(const u32x2*)&Vt[cur][dt * 16 + c][kt * 32 + 4 * g];
        u32x2 vhi = *(const u32x2*)&Vt[cur][dt * 16 + c][kt * 32 + 16 + 4 * g];
        u32x4 vau = {vlo.x, vlo.y, vhi.x, vhi.y};
        va = __builtin_bit_cast(bf16x8, vau);
      }
      acc[dt] = __builtin_amdgcn_mfma_f32_16x16x32_bf16(va, wb, acc[dt], 0, 0, 0);
    }
    __builtin_amdgcn_s_setprio(0);

    if (it + 1 < NIT) writeKV((it + 1) & 1);
    TILE_BARRIER();
  }

  // ---- combine ctx partials across k-halves through LDS (Kt reused) ----
  float* red = (float*)&Kt[0][0][0] + wq * 1088;  // 16 rows x 68 f32 per pair
  if (kt == 1) {
#pragma unroll
    for (int dt = 0; dt < 4; ++dt)
      *(f32x4*)&red[c * 68 + dt * 16 + 4 * g] = acc[dt];
  }
  __syncthreads();
  if (kt == 0) {
    float* crow = ctx + (bq + q0w + c) * ND;
#pragma unroll
    for (int dt = 0; dt < 4; ++dt) {
      f32x4 vv = acc[dt] + *(const f32x4*)&red[c * 68 + dt * 16 + 4 * g];
      __builtin_nontemporal_store(vv, (f32x4*)(crow + dt * 16 + 4 * g));
    }
  }
}

extern "C" void kernel_launch(void* const* d_in, const int* in_sizes, int n_in,
                              void* d_out, int out_size, void* d_ws, size_t ws_size,
                              hipStream_t stream) {
  const float* Q = (const float*)d_in[0];
  const float* K = (const float*)d_in[1];
  const float* V = (const float*)d_in[2];
  const int*   M = (const int*)d_in[3];
  float* ctx = (float*)d_out;                         // [B,S,D]
  float* wts = (float*)d_out + (size_t)NB * NS * ND;  // [B,S,S]

  dim3 grid(NB * (NS / 64));  // 2048
  dim3 block(512);

  constexpr size_t KBF_B = (size_t)NB * NS * ND * 2;     // 16.78 MB
  constexpr size_t MB_B  = (size_t)NS * NS / 8;          // 0.52 MB
  u16* Kbf = (u16*)d_ws;
  u16* VTb = (u16*)((char*)d_ws + KBF_B);
  u32* Mb32 = (u32*)((char*)d_ws + 2 * KBF_B);

  if (ws_size >= 2 * KBF_B + MB_B) {
    hipLaunchKernelGGL(prep_fused, dim3(6656), dim3(256), 0, stream, K, V, M, Kbf, VTb, Mb32);
    hipLaunchKernelGGL(DotProductAttention_22436909154804_kernel<true>, grid, block, 0, stream,
                       Q, K, V, M, Kbf, VTb, Mb32, ctx, wts);
  } else {
    hipLaunchKernelGGL(DotProductAttention_22436909154804_kernel<false>, grid, block, 0, stream,
                       Q, K, V, M, (const u16*)nullptr, (const u16*)nullptr,
                       (const u32*)nullptr, ctx, wts);
  }
}

// Round 11
// 335.742 us; speedup vs baseline: 1.1511x; 1.1511x over previous
//
#include <hip/hip_runtime.h>

#define NB 64
#define NS 2048
#define ND 64
#define KSTEP 64
#define NIT (NS / KSTEP)  // 32

typedef __bf16 bf16x8 __attribute__((ext_vector_type(8)));
typedef float f32x4 __attribute__((ext_vector_type(4)));
typedef unsigned int u32;
typedef u32 u32x2 __attribute__((ext_vector_type(2)));
typedef u32 u32x4 __attribute__((ext_vector_type(4)));
typedef unsigned short u16;
typedef u16 u16x8 __attribute__((ext_vector_type(8)));

#define C2F 0.18033688011112042f  // log2(e)/8

__device__ __forceinline__ float fexp2(float x) {
#if __has_builtin(__builtin_amdgcn_exp2f)
  return __builtin_amdgcn_exp2f(x);
#else
  return exp2f(x);
#endif
}
__device__ __forceinline__ float flog2(float x) {
#if __has_builtin(__builtin_amdgcn_logf)
  return __builtin_amdgcn_logf(x);
#else
  return log2f(x);
#endif
}

// Barrier without the vmcnt(0) drain __syncthreads imposes (r8: -55us).
#define TILE_BARRIER()                                   \
  do {                                                   \
    asm volatile("s_waitcnt lgkmcnt(0)" ::: "memory");   \
    __builtin_amdgcn_s_barrier();                        \
    asm volatile("" ::: "memory");                       \
  } while (0)

__device__ __forceinline__ u16 f2bs(float x) {
  __bf16 h = (__bf16)x;
  return __builtin_bit_cast(u16, h);
}

__device__ __forceinline__ bf16x8 cvt8(f32x4 a, f32x4 b) {
  bf16x8 r;
  r[0] = (__bf16)a[0]; r[1] = (__bf16)a[1]; r[2] = (__bf16)a[2]; r[3] = (__bf16)a[3];
  r[4] = (__bf16)b[0]; r[5] = (__bf16)b[1]; r[6] = (__bf16)b[2]; r[7] = (__bf16)b[3];
  return r;
}

// ---------- prep 1: K fp32 -> bf16 ----------
__global__ __launch_bounds__(256) void prep_cast_k(const float* __restrict__ K,
                                                   u16* __restrict__ Kbf) {
  const size_t i = ((size_t)blockIdx.x * 256 + threadIdx.x) * 8;
  f32x4 a = __builtin_nontemporal_load((const f32x4*)(K + i));
  f32x4 b = __builtin_nontemporal_load((const f32x4*)(K + i + 4));
  *(bf16x8*)(Kbf + i) = cvt8(a, b);
}

// ---------- prep 2: V fp32 [b][k][d] -> bf16 V^T [b][d][perm k] ----------
// Column permutation within each 32-k window: position p holds
// k_local = 16*((p>>2)&1) + 4*((p>>3)&3) + (p&3), so the kernel's PV
// A-operand is ONE ds_read_b128 at col 8g..8g+7 per 32-window.
__global__ __launch_bounds__(256) void prep_transp_v(const float* __restrict__ V,
                                                     u16* __restrict__ VT) {
  __shared__ __attribute__((aligned(16))) u16 T[64][72];
  const int b = blockIdx.x >> 5, kt = blockIdx.x & 31;
  const float* src = V + ((size_t)b * NS + kt * 64) * ND;
  {
    const int k = threadIdx.x >> 2, d0 = (threadIdx.x & 3) * 16;
    const float* p = src + (size_t)k * ND + d0;
    f32x4 a0 = __builtin_nontemporal_load((const f32x4*)p);
    f32x4 a1 = __builtin_nontemporal_load((const f32x4*)(p + 4));
    f32x4 a2 = __builtin_nontemporal_load((const f32x4*)(p + 8));
    f32x4 a3 = __builtin_nontemporal_load((const f32x4*)(p + 12));
    *(bf16x8*)&T[k][d0]     = cvt8(a0, a1);
    *(bf16x8*)&T[k][d0 + 8] = cvt8(a2, a3);
  }
  __syncthreads();
  const int d = threadIdx.x >> 2, k0 = (threadIdx.x & 3) * 16;
  u16x8 r0, r1;
#pragma unroll
  for (int j = 0; j < 8; ++j) {
    const int P0 = k0 + j, P1 = k0 + 8 + j;
    const int s0 = 32 * (P0 >> 5) + 16 * ((P0 >> 2) & 1) + 4 * ((P0 >> 3) & 3) + (P0 & 3);
    const int s1 = 32 * (P1 >> 5) + 16 * ((P1 >> 2) & 1) + 4 * ((P1 >> 3) & 3) + (P1 & 3);
    r0[j] = T[s0][d];
    r1[j] = T[s1][d];
  }
  u16* dst = VT + ((size_t)b * ND + d) * NS + kt * 64 + k0;
  *(u16x8*)dst = r0;
  *(u16x8*)(dst + 8) = r1;
}

// ---------- prep 3: int mask -> bit mask ----------
__global__ __launch_bounds__(256) void prep_pack_mask(const int* __restrict__ M,
                                                      unsigned long long* __restrict__ Mb) {
  const size_t i = (size_t)blockIdx.x * 256 + threadIdx.x;
  const unsigned long long bal = __ballot(M[i] != 0);
  if ((threadIdx.x & 63) == 0) Mb[i >> 6] = bal;
}

// K-SPLIT structure (r9, 346us): 512 thr / 8 waves / 64 q-rows, 2048 blocks.
// Waves (wq, kt): wq = w&3 -> 16-q-row subtile; kt = w>>2 -> k-half of each
// K tile. 3 blk/CU -> 3 batches resident/XCD -> bf16 K/V L2-resident.
// r11 change: phase 1 overlays Kt+Vt as a QUAD buffer -> KSTEP1=128, 16
// barriers instead of 32 (phase 1 is K-only, Vt was idle). Phase 2 = r9.
// r10 lesson: NO hand-written cvt_pk (m240: -37%), NO setprio in lockstep
// loops (m190: null-to-negative without wave role-split).
// mfma_f32_16x16x32_bf16 facts (HW-verified r1-2): A[row=l&15][k=8g+s],
// B[k=8g+s][col=l&15], D[m=4g+reg][n=l&15]. QK^T role-swapped (A=K,B=Q):
// lane owns W[q=c][k=kt*32+16j+4g+r]; W feeds PV's B-operand from registers.
template <bool PRE>
__global__ __launch_bounds__(512, 3) void DotProductAttention_22436909154804_kernel(
    const float* __restrict__ Q, const float* __restrict__ K,
    const float* __restrict__ V, const int* __restrict__ M,
    const u16* __restrict__ Kbf, const u16* __restrict__ VTbf,
    const u32* __restrict__ Mb, float* __restrict__ ctx, float* __restrict__ wts) {
  __shared__ __attribute__((aligned(16))) u16 Kt[2][64][72];  // [k][d]
  __shared__ __attribute__((aligned(16))) u16 Vt[2][64][72];  // [d][perm k] (ph2); K quad-buf (ph1)
  __shared__ float Rs[2][64];

  const int tid  = threadIdx.x;
  const int lane = tid & 63;
  const int w    = tid >> 6;   // 0..7
  const int wq   = w & 3;      // q-subtile
  const int kt   = w >> 2;     // k-half
  const int g    = lane >> 4;  // 0..3
  const int c    = lane & 15;  // 0..15

  // XCD swizzle: 2048 blocks = 8 XCDs x 256; consecutive vb share a batch.
  const int bid = blockIdx.x;
  const int vb  = (bid & 7) * 256 + (bid >> 3);
  const int b   = vb >> 5;
  const int qt  = vb & 31;
  const int q0w = qt * 64 + wq * 16;
  const size_t bq = (size_t)b * NS;

  // Q B-frags
  const float* qp = Q + (bq + q0w + c) * ND + 8 * g;
  f32x4 qa = __builtin_nontemporal_load((const f32x4*)qp);
  f32x4 qb = __builtin_nontemporal_load((const f32x4*)(qp + 4));
  const bf16x8 qf0 = cvt8(qa, qb);
  qa = __builtin_nontemporal_load((const f32x4*)(qp + 32));
  qb = __builtin_nontemporal_load((const f32x4*)(qp + 36));
  const bf16x8 qf1 = cvt8(qa, qb);

  const u16* Kbb = PRE ? (Kbf + bq * ND) : (const u16*)nullptr;
  const u16* VTb = PRE ? (VTbf + bq * ND) : (const u16*)nullptr;
  const float* Kb32 = K + bq * ND;
  const float* Vb32 = V + bq * ND;
  const int* Mr   = M + (size_t)(q0w + c) * NS + kt * 32;
  const u32* MbRow = Mb + (size_t)(q0w + c) * (NS / 32);
  const u32* Mbr   = MbRow + kt;

  const bool isK = tid < 256;
  const int st   = tid & 255;

  auto msel = [](float e, u32 mm, int idx) -> float {
    u32 keep = (u32)(((int)(mm << (31 - idx))) >> 31);
    return __uint_as_float(__float_as_uint(e) & keep);
  };

  const f32x4 zz = {0.f, 0.f, 0.f, 0.f};
  float rs = 0.f;

  // ================ Phase 1: row sums (per k-half) ================
  if (PRE) {
    // KSTEP1 = 128 via quad-buffer overlay: pair 0 = (Kt[0],Kt[1]),
    // pair 1 = (Vt[0],Vt[1]); within a pair, rows 0-63 / 64-127.
    const int r1  = tid >> 2;        // 0..127
    const int cc1 = (tid & 3) * 16;  // 0,16,32,48
    u16x8 pa, pb;
    auto issueP1 = [&](int kb) {
      const u16* p = Kbb + (size_t)(kb + r1) * ND + cc1;
      pa = *(const u16x8*)p;
      pb = *(const u16x8*)(p + 8);
    };
    auto writeP1 = [&](int pair) {
      u16(*dst)[72] = pair ? Vt[r1 >> 6] : Kt[r1 >> 6];
      *(u16x8*)&dst[r1 & 63][cc1]     = pa;
      *(u16x8*)&dst[r1 & 63][cc1 + 8] = pb;
    };
    issueP1(0);
    writeP1(0);
    __syncthreads();
    for (int it = 0; it < 16; ++it) {
      const int pair = it & 1;
      if (it + 1 < 16) issueP1((it + 1) * 128);
      const u32x2 mv = *(const u32x2*)(MbRow + it * 4 + kt * 2);
      u16(*B)[72] = pair ? Vt[kt] : Kt[kt];  // this wave's 64-row k-half
#pragma unroll
      for (int j = 0; j < 4; ++j) {
        bf16x8 a0 = *(const bf16x8*)&B[16 * j + c][8 * g];
        bf16x8 a1 = *(const bf16x8*)&B[16 * j + c][32 + 8 * g];
        f32x4 s = __builtin_amdgcn_mfma_f32_16x16x32_bf16(a0, qf0, zz, 0, 0, 0);
        s = __builtin_amdgcn_mfma_f32_16x16x32_bf16(a1, qf1, s, 0, 0, 0);
        const u32 mm = (j < 2) ? mv.x : mv.y;
        const int base = 16 * (j & 1) + 4 * g;
        rs += msel(fexp2(s[0] * C2F), mm, base + 0)
            + msel(fexp2(s[1] * C2F), mm, base + 1)
            + msel(fexp2(s[2] * C2F), mm, base + 2)
            + msel(fexp2(s[3] * C2F), mm, base + 3);
      }
      if (it + 1 < 16) writeP1((it + 1) & 1);
      TILE_BARRIER();
    }
  } else {
    // fallback: r9 KSTEP=64 K-only staging
    f32x4 kf0, kf1, kf2, kf3;
    auto issueK1 = [&](int kb) {
      if (isK) {
        const int r = st >> 2, cc = (st & 3) * 16;
        const float* p = Kb32 + (size_t)(kb + r) * ND + cc;
        kf0 = *(const f32x4*)p;       kf1 = *(const f32x4*)(p + 4);
        kf2 = *(const f32x4*)(p + 8); kf3 = *(const f32x4*)(p + 12);
      }
    };
    auto writeK1 = [&](int buf) {
      if (isK) {
        const int r = st >> 2, cc = (st & 3) * 16;
        *(bf16x8*)&Kt[buf][r][cc]     = cvt8(kf0, kf1);
        *(bf16x8*)&Kt[buf][r][cc + 8] = cvt8(kf2, kf3);
      }
    };
    issueK1(0);
    writeK1(0);
    __syncthreads();
    for (int it = 0; it < NIT; ++it) {
      const int cur = it & 1, kb = it * KSTEP;
      if (it + 1 < NIT) issueK1(kb + KSTEP);
#pragma unroll
      for (int j = 0; j < 2; ++j) {
        bf16x8 a0 = *(const bf16x8*)&Kt[cur][kt * 32 + 16 * j + c][8 * g];
        bf16x8 a1 = *(const bf16x8*)&Kt[cur][kt * 32 + 16 * j + c][32 + 8 * g];
        f32x4 s = __builtin_amdgcn_mfma_f32_16x16x32_bf16(a0, qf0, zz, 0, 0, 0);
        s = __builtin_amdgcn_mfma_f32_16x16x32_bf16(a1, qf1, s, 0, 0, 0);
        const int4 m4 = *(const int4*)(Mr + kb + 16 * j + 4 * g);
        rs += (m4.x ? fexp2(s[0] * C2F) : 0.f)
            + (m4.y ? fexp2(s[1] * C2F) : 0.f)
            + (m4.z ? fexp2(s[2] * C2F) : 0.f)
            + (m4.w ? fexp2(s[3] * C2F) : 0.f);
      }
      if (it + 1 < NIT) writeK1((it + 1) & 1);
      TILE_BARRIER();
    }
  }
  rs += __shfl_xor(rs, 16);
  rs += __shfl_xor(rs, 32);

  // ---- phase-2 staging lambdas (r9) ----
  u16x8 sp0, sp1;            // PRE payloads
  f32x4 kf0, kf1, kf2, kf3;  // !PRE payloads
  auto issueKV = [&](int kb) {  // K by waves 0-3, V by waves 4-7
    if (PRE) {
      if (isK) {
        const int r = st >> 2, cc = (st & 3) * 16;
        const u16* p = Kbb + (size_t)(kb + r) * ND + cc;
        sp0 = *(const u16x8*)p; sp1 = *(const u16x8*)(p + 8);
      } else {
        const int d = st >> 2, kc = (st & 3) * 16;
        const u16* p = VTb + (size_t)d * NS + kb + kc;
        sp0 = *(const u16x8*)p; sp1 = *(const u16x8*)(p + 8);
      }
    } else {
      if (isK) {
        const int r = st >> 2, cc = (st & 3) * 16;
        const float* p = Kb32 + (size_t)(kb + r) * ND + cc;
        kf0 = *(const f32x4*)p;       kf1 = *(const f32x4*)(p + 4);
        kf2 = *(const f32x4*)(p + 8); kf3 = *(const f32x4*)(p + 12);
      } else {
        const int k = st >> 2, d0 = (st & 3) * 16;
        const float* p = Vb32 + (size_t)(kb + k) * ND + d0;
        kf0 = *(const f32x4*)p;       kf1 = *(const f32x4*)(p + 4);
        kf2 = *(const f32x4*)(p + 8); kf3 = *(const f32x4*)(p + 12);
      }
    }
  };
  auto writeKV = [&](int buf) {
    if (PRE) {
      if (isK) {
        const int r = st >> 2, cc = (st & 3) * 16;
        *(u16x8*)&Kt[buf][r][cc] = sp0; *(u16x8*)&Kt[buf][r][cc + 8] = sp1;
      } else {
        const int d = st >> 2, kc = (st & 3) * 16;
        *(u16x8*)&Vt[buf][d][kc] = sp0; *(u16x8*)&Vt[buf][d][kc + 8] = sp1;
      }
    } else {
      if (isK) {
        const int r = st >> 2, cc = (st & 3) * 16;
        *(bf16x8*)&Kt[buf][r][cc]     = cvt8(kf0, kf1);
        *(bf16x8*)&Kt[buf][r][cc + 8] = cvt8(kf2, kf3);
      } else {
        const int k = st >> 2, d0 = (st & 3) * 16;
        bf16x8 v0 = cvt8(kf0, kf1), v1 = cvt8(kf2, kf3);
#pragma unroll
        for (int j = 0; j < 8; ++j) {
          Vt[buf][d0 + j][k]     = __builtin_bit_cast(u16, v0[j]);
          Vt[buf][d0 + 8 + j][k] = __builtin_bit_cast(u16, v1[j]);
        }
      }
    }
  };

  issueKV(0);
  if (lane < 16) Rs[kt][wq * 16 + c] = rs;
  __syncthreads();
  const float l2inv = -flog2(Rs[0][wq * 16 + c] + Rs[1][wq * 16 + c]);
  writeKV(0);
  __syncthreads();

  // ================ Phase 2: weights + PV (per k-half partials) ================
  f32x4 acc[4] = {zz, zz, zz, zz};
  float* wrow = wts + (bq + q0w + c) * NS + kt * 32;
  for (int it = 0; it < NIT; ++it) {
    const int cur = it & 1, kb = it * KSTEP;
    if (it + 1 < NIT) issueKV(kb + KSTEP);
    u32 mm = 0;
    if (PRE) mm = Mbr[kb >> 5];

    u32 wpk[4];
#pragma unroll
    for (int j = 0; j < 2; ++j) {
      bf16x8 a0 = *(const bf16x8*)&Kt[cur][kt * 32 + 16 * j + c][8 * g];
      bf16x8 a1 = *(const bf16x8*)&Kt[cur][kt * 32 + 16 * j + c][32 + 8 * g];
      f32x4 s = __builtin_amdgcn_mfma_f32_16x16x32_bf16(a0, qf0, zz, 0, 0, 0);
      s = __builtin_amdgcn_mfma_f32_16x16x32_bf16(a1, qf1, s, 0, 0, 0);
      float w0, w1, w2, w3;
      if (PRE) {
        w0 = msel(fexp2(fmaf(s[0], C2F, l2inv)), mm, 16 * j + 4 * g + 0);
        w1 = msel(fexp2(fmaf(s[1], C2F, l2inv)), mm, 16 * j + 4 * g + 1);
        w2 = msel(fexp2(fmaf(s[2], C2F, l2inv)), mm, 16 * j + 4 * g + 2);
        w3 = msel(fexp2(fmaf(s[3], C2F, l2inv)), mm, 16 * j + 4 * g + 3);
      } else {
        const int4 m4 = *(const int4*)(Mr + kb + 16 * j + 4 * g);
        w0 = m4.x ? fexp2(fmaf(s[0], C2F, l2inv)) : 0.f;
        w1 = m4.y ? fexp2(fmaf(s[1], C2F, l2inv)) : 0.f;
        w2 = m4.z ? fexp2(fmaf(s[2], C2F, l2inv)) : 0.f;
        w3 = m4.w ? fexp2(fmaf(s[3], C2F, l2inv)) : 0.f;
      }
      f32x4 wv = {w0, w1, w2, w3};
      __builtin_nontemporal_store(wv, (f32x4*)(wrow + kb + 16 * j + 4 * g));
      wpk[2 * j]     = (u32)f2bs(w0) | ((u32)f2bs(w1) << 16);
      wpk[2 * j + 1] = (u32)f2bs(w2) | ((u32)f2bs(w3) << 16);
    }

    // PV partial for this wave's k-half; B = W from registers
    u32x4 wu = {wpk[0], wpk[1], wpk[2], wpk[3]};
    bf16x8 wb = __builtin_bit_cast(bf16x8, wu);
#pragma unroll
    for (int dt = 0; dt < 4; ++dt) {
      bf16x8 va;
      if (PRE) {
        va = *(const bf16x8*)&Vt[cur][dt * 16 + c][kt * 32 + 8 * g];
      } else {
        u32x2 vlo = *(const u32x2*)&Vt[cur][dt * 16 + c][kt * 32 + 4 * g];
        u32x2 vhi = *(const u32x2*)&Vt[cur][dt * 16 + c][kt * 32 + 16 + 4 * g];
        u32x4 vau = {vlo.x, vlo.y, vhi.x, vhi.y};
        va = __builtin_bit_cast(bf16x8, vau);
      }
      acc[dt] = __builtin_amdgcn_mfma_f32_16x16x32_bf16(va, wb, acc[dt], 0, 0, 0);
    }

    if (it + 1 < NIT) writeKV((it + 1) & 1);
    TILE_BARRIER();
  }

  // ---- combine ctx partials across k-halves through LDS (Kt reused) ----
  float* red = (float*)&Kt[0][0][0] + wq * 1088;  // 16 rows x 68 f32 per pair
  if (kt == 1) {
#pragma unroll
    for (int dt = 0; dt < 4; ++dt)
      *(f32x4*)&red[c * 68 + dt * 16 + 4 * g] = acc[dt];
  }
  __syncthreads();
  if (kt == 0) {
    float* crow = ctx + (bq + q0w + c) * ND;
#pragma unroll
    for (int dt = 0; dt < 4; ++dt) {
      f32x4 vv = acc[dt] + *(const f32x4*)&red[c * 68 + dt * 16 + 4 * g];
      __builtin_nontemporal_store(vv, (f32x4*)(crow + dt * 16 + 4 * g));
    }
  }
}

extern "C" void kernel_launch(void* const* d_in, const int* in_sizes, int n_in,
                              void* d_out, int out_size, void* d_ws, size_t ws_size,
                              hipStream_t stream) {
  const float* Q = (const float*)d_in[0];
  const float* K = (const float*)d_in[1];
  const float* V = (const float*)d_in[2];
  const int*   M = (const int*)d_in[3];
  float* ctx = (float*)d_out;                         // [B,S,D]
  float* wts = (float*)d_out + (size_t)NB * NS * ND;  // [B,S,S]

  dim3 grid(NB * (NS / 64));  // 2048
  dim3 block(512);

  constexpr size_t KBF_B = (size_t)NB * NS * ND * 2;     // 16.78 MB
  constexpr size_t MB_B  = (size_t)NS * NS / 8;          // 0.52 MB
  u16* Kbf = (u16*)d_ws;
  u16* VTb = (u16*)((char*)d_ws + KBF_B);
  unsigned long long* Mb64 = (unsigned long long*)((char*)d_ws + 2 * KBF_B);

  if (ws_size >= 2 * KBF_B + MB_B) {
    hipLaunchKernelGGL(prep_cast_k, dim3(NB * NS * ND / 8 / 256), dim3(256), 0, stream, K, Kbf);
    hipLaunchKernelGGL(prep_transp_v, dim3(NB * (NS / 64)), dim3(256), 0, stream, V, VTb);
    hipLaunchKernelGGL(prep_pack_mask, dim3(NS * NS / 256), dim3(256), 0, stream, M, Mb64);
    hipLaunchKernelGGL(DotProductAttention_22436909154804_kernel<true>, grid, block, 0, stream,
                       Q, K, V, M, Kbf, VTb, (const u32*)Mb64, ctx, wts);
  } else {
    hipLaunchKernelGGL(DotProductAttention_22436909154804_kernel<false>, grid, block, 0, stream,
                       Q, K, V, M, (const u16*)nullptr, (const u16*)nullptr,
                       (const u32*)nullptr, ctx, wts);
  }
}